// Round 12
// baseline (206.490 us; speedup 1.0000x reference)
//
#include <hip/hip_runtime.h>
#include <hip/hip_bf16.h>

#define K_DIM 2048
#define N_DIM 128
#define BM 32
#define BK 64
#define NTILES (K_DIM / BK)        // 32
#define VT_CHUNK 16384             // 128 n * 64 k * 2B per k-chunk

typedef __bf16 bf16x8 __attribute__((ext_vector_type(8)));
typedef float f32x4 __attribute__((ext_vector_type(4)));

__device__ __forceinline__ float dot4(f32x4 a, f32x4 b) {
    return a.x * b.x + a.y * b.y + a.z * b.z + a.w * b.w;
}

__device__ __forceinline__ void gload16(const void* g, void* lds) {
    __builtin_amdgcn_global_load_lds(
        (const __attribute__((address_space(1))) unsigned int*)g,
        (__attribute__((address_space(3))) unsigned int*)lds,
        16, 0, 0);
}

// ---- prep: VtS[chunk kb][byte n*128 + ((kk*2) ^ ((n&7)<<4))] = bf16(V[kb*64+kk][n])
// (the swizzled LDS image itself, so main stages it with linear gload_lds)
// plus s[k] = sum_n V[k][n]^2
__global__ __launch_bounds__(256) void fm_prep(const float* __restrict__ V,
                                               char* __restrict__ VtS,
                                               float* __restrict__ s) {
    __shared__ float tile[64][132];
    const int t = threadIdx.x;
    const int kb = blockIdx.x;            // 32 blocks
    const int k0 = kb * 64;
#pragma unroll
    for (int i = 0; i < 8; ++i) {
        int idx = i * 256 + t;
        int kk = idx >> 5;
        int nq = (idx & 31) * 4;
        *(f32x4*)&tile[kk][nq] = *(const f32x4*)(V + (size_t)(k0 + kk) * N_DIM + nq);
    }
    __syncthreads();
    {
        const int n = t >> 1;
        const int half = t & 1;
        const int sw = (n & 7) << 4;
        char* dstbase = VtS + (size_t)kb * VT_CHUNK + n * 128;
#pragma unroll
        for (int g = 0; g < 4; ++g) {
            int kkg = half * 32 + g * 8;
            bf16x8 o;
#pragma unroll
            for (int e = 0; e < 8; ++e) o[e] = (__bf16)tile[kkg + e][n];
            *(bf16x8*)(dstbase + ((kkg * 2) ^ sw)) = o;
        }
    }
    if (t < 64) {
        float a = 0.f;
#pragma unroll
        for (int nq = 0; nq < 32; ++nq) {
            f32x4 v = *(f32x4*)&tile[t][nq * 4];
            a += dot4(v, v);
        }
        s[k0 + t] = a;
    }
}

// ---- main: block = 32 rows x 128 n x full K, 8 waves. R6 post-mortem: the
// __syncthreads() per tile lowered to s_waitcnt vmcnt(0)+s_barrier, draining
// the just-issued prefetch every tile -> wall = 32 x (HBM latency + compute)
// regardless of blocks/CU (R4==R6 exactly). Fix (T3/T4 minimum form): raw
// s_barrier + counted per-wave vmcnt. x 3-deep (issue t+2, wait vmcnt(2) ->
// t+1 ready, ~2 tile-times covers ~900cy HBM); Vt 2-deep, vmcnt(0) (L2-res).
// Each wave drains its OWN loads pre-barrier (vmcnt FIFO, m135); prologue
// lgkmcnt(0) covers Wl/Sl ds_writes cross-wave.
__global__ __launch_bounds__(512, 4) void fm_main(const float* __restrict__ x,
                                                  const float* __restrict__ W,
                                                  const float* __restrict__ bptr,
                                                  const char* __restrict__ VtS,
                                                  const float* __restrict__ s,
                                                  float* __restrict__ out) {
    __shared__ __align__(16) char xbuf[3][8192];    // [32 rows][256B] swizzled, 3-deep
    __shared__ __align__(16) char vbuf[2][16384];   // [128 n][128B] swizzled, 2-deep
    __shared__ __align__(16) float Wl[2048];
    __shared__ __align__(16) float Sl[2048];
    __shared__ float lin_lds[2][16];
    __shared__ float sq_lds[2][16];
    __shared__ float ss_lds[2][4][16];

    const int tid = threadIdx.x;
    const int w = tid >> 6;
    const int l = tid & 63;
    const int lr = l & 15;
    const int lg = l >> 4;
    const int wr = w >> 2;      // 0..1 : row-group of 16
    const int wc = w & 3;       // 0..3 : n-group of 32
    const int row0 = blockIdx.x * BM;

    // W, s -> LDS first (their vmem waits retire before the pipeline gloads,
    // keeping our asm vmcnt counts exact)
    *(f32x4*)&Wl[tid * 4] = *(const f32x4*)(W + tid * 4);
    *(f32x4*)&Sl[tid * 4] = *(const f32x4*)(s + tid * 4);

    // ---- staging: waves 0-3 stage x (2 instrs/tile), waves 4-7 stage Vt (4/tile)
    const bool isX = (w < 4);
    const char* src[4];
    int loff[4];
    if (isX) {
#pragma unroll
        for (int j = 0; j < 2; ++j) {
            int gi = w * 2 + j;                 // 0..7
            int rowt = gi * 4 + lg;             // tile row this lane stages
            int koff = (lr * 16) ^ ((rowt & 7) << 4);   // inverse-swizzled source
            src[j] = (const char*)x + (size_t)(row0 + rowt) * (K_DIM * 4) + koff;
            loff[j] = gi * 1024;
        }
    } else {
#pragma unroll
        for (int j = 0; j < 4; ++j) {
            int vi = (w - 4) * 4 + j;           // 0..15
            src[j] = VtS + vi * 1024 + l * 16;  // linear: global IS the LDS image
            loff[j] = vi * 1024;
        }
    }

    f32x4 acc[2];
    acc[0] = (f32x4){0.f, 0.f, 0.f, 0.f};
    acc[1] = (f32x4){0.f, 0.f, 0.f, 0.f};
    float lin = 0.f, sq = 0.f;

    // prologue: x tiles 0,1 -> slots 0,1 (keep tile1 in flight); Vt tile 0
    if (isX) {
#pragma unroll
        for (int j = 0; j < 2; ++j) gload16(src[j], &xbuf[0][loff[j]]);
#pragma unroll
        for (int j = 0; j < 2; ++j) gload16(src[j] + 256, &xbuf[1][loff[j]]);
        asm volatile("s_waitcnt vmcnt(2) lgkmcnt(0)" ::: "memory");
    } else {
#pragma unroll
        for (int j = 0; j < 4; ++j) gload16(src[j], &vbuf[0][loff[j]]);
        asm volatile("s_waitcnt vmcnt(0) lgkmcnt(0)" ::: "memory");
    }
    __builtin_amdgcn_s_barrier();
    __builtin_amdgcn_sched_barrier(0);

    const int rowt = wr * 16 + lr;
    const int swA = (rowt & 7) << 4;

    int xr = 0, xi = 2, vr = 0;
    for (int t = 0; t < NTILES; ++t) {
        // issue-ahead: x[t+2] -> slot xi, Vt[t+1] -> other v-slot
        if (isX) {
            if (t + 2 < NTILES) {
#pragma unroll
                for (int j = 0; j < 2; ++j)
                    gload16(src[j] + (size_t)(t + 2) * (BK * 4), &xbuf[xi][loff[j]]);
            }
        } else {
            if (t + 1 < NTILES) {
#pragma unroll
                for (int j = 0; j < 4; ++j)
                    gload16(src[j] + (size_t)(t + 1) * VT_CHUNK, &vbuf[vr ^ 1][loff[j]]);
            }
        }

        // ---- compute tile t
        const char* arow = &xbuf[xr][0] + rowt * 256;
        const char* vb = &vbuf[vr][0];

        bf16x8 af[2];
        f32x4 alo[2], ahi[2];
#pragma unroll
        for (int kb = 0; kb < 2; ++kb) {
            const int kA = kb * 128 + lg * 32;
            alo[kb] = *(const f32x4*)(arow + (kA ^ swA));
            ahi[kb] = *(const f32x4*)(arow + ((kA + 16) ^ swA));
            af[kb][0] = (__bf16)alo[kb].x; af[kb][1] = (__bf16)alo[kb].y;
            af[kb][2] = (__bf16)alo[kb].z; af[kb][3] = (__bf16)alo[kb].w;
            af[kb][4] = (__bf16)ahi[kb].x; af[kb][5] = (__bf16)ahi[kb].y;
            af[kb][6] = (__bf16)ahi[kb].z; af[kb][7] = (__bf16)ahi[kb].w;
        }
        if (wc == 0) {   // one n-group owns the lin/sq accumulation
            const int ki = t * 64 + lg * 8;
#pragma unroll
            for (int kb = 0; kb < 2; ++kb) {
                f32x4 w0 = *(const f32x4*)&Wl[ki + kb * 32];
                f32x4 w1 = *(const f32x4*)&Wl[ki + kb * 32 + 4];
                f32x4 s0 = *(const f32x4*)&Sl[ki + kb * 32];
                f32x4 s1 = *(const f32x4*)&Sl[ki + kb * 32 + 4];
                lin += dot4(alo[kb], w0) + dot4(ahi[kb], w1);
                sq  += dot4(alo[kb] * alo[kb], s0) + dot4(ahi[kb] * ahi[kb], s1);
            }
        }
#pragma unroll
        for (int c = 0; c < 2; ++c) {
            const int nt = wc * 32 + c * 16 + lr;
            const int swB = (nt & 7) << 4;
            const char* brow = vb + nt * 128;
#pragma unroll
            for (int kb = 0; kb < 2; ++kb) {
                bf16x8 bf = *(const bf16x8*)(brow + ((kb * 64 + lg * 16) ^ swB));
                acc[c] = __builtin_amdgcn_mfma_f32_16x16x32_bf16(af[kb], bf, acc[c], 0, 0, 0);
            }
        }

        // ---- counted-vmcnt sync: t+1's data ready, t+2's stays in flight
        if (t < NTILES - 1) {
            if (isX) {
                if (t + 2 < NTILES)
                    asm volatile("s_waitcnt vmcnt(2)" ::: "memory");
                else
                    asm volatile("s_waitcnt vmcnt(0)" ::: "memory");
            } else {
                asm volatile("s_waitcnt vmcnt(0)" ::: "memory");
            }
            __builtin_amdgcn_s_barrier();
            __builtin_amdgcn_sched_barrier(0);
        }
        xr = (xr == 2) ? 0 : xr + 1;
        xi = (xi == 2) ? 0 : xi + 1;
        vr ^= 1;
    }

    // ---- epilogue. C/D layout (m89, verified R2/R4/R6): out-row = lg*4+j, out-col(n) = lr
    f32x4 vss = acc[0] * acc[0] + acc[1] * acc[1];
#pragma unroll
    for (int m = 1; m < 16; m <<= 1) {
        vss.x += __shfl_xor(vss.x, m);
        vss.y += __shfl_xor(vss.y, m);
        vss.z += __shfl_xor(vss.z, m);
        vss.w += __shfl_xor(vss.w, m);
    }
    if (lr == 0) {
        ss_lds[wr][wc][lg * 4 + 0] = vss.x;
        ss_lds[wr][wc][lg * 4 + 1] = vss.y;
        ss_lds[wr][wc][lg * 4 + 2] = vss.z;
        ss_lds[wr][wc][lg * 4 + 3] = vss.w;
    }
    if (wc == 0) {
        lin += __shfl_xor(lin, 16); lin += __shfl_xor(lin, 32);
        sq  += __shfl_xor(sq, 16);  sq  += __shfl_xor(sq, 32);
        if (l < 16) { lin_lds[wr][l] = lin; sq_lds[wr][l] = sq; }
    }
    __syncthreads();
    if (tid < BM) {
        const int wrI = tid >> 4, r16 = tid & 15;
        out[row0 + tid] = lin_lds[wrI][r16] + bptr[0]
            + 0.5f * (ss_lds[wrI][0][r16] + ss_lds[wrI][1][r16]
                      + ss_lds[wrI][2][r16] + ss_lds[wrI][3][r16]
                      - sq_lds[wrI][r16]);
    }
}

extern "C" void kernel_launch(void* const* d_in, const int* in_sizes, int n_in,
                              void* d_out, int out_size, void* d_ws, size_t ws_size,
                              hipStream_t stream) {
    const float* x = (const float*)d_in[0];
    const float* W = (const float*)d_in[1];
    const float* b = (const float*)d_in[2];
    const float* V = (const float*)d_in[3];
    float* out = (float*)d_out;

    char* VtS = (char*)d_ws;                                  // 32 chunks * 16KB = 512KB
    float* s = (float*)((char*)d_ws + 32 * VT_CHUNK);         // 8KB

    fm_prep<<<32, 256, 0, stream>>>(V, VtS, s);
    fm_main<<<512, 512, 0, stream>>>(x, W, b, VtS, s, out);
}

// Round 13
// 203.513 us; speedup vs baseline: 1.0146x; 1.0146x over previous
//
#include <hip/hip_runtime.h>
#include <hip/hip_bf16.h>

#define K_DIM 2048
#define N_DIM 128
#define BM 64
#define BK 64
#define NTILES (K_DIM / BK)        // 32
#define VT_CHUNK 16384             // 128 n * 64 k * 2B per k-chunk

typedef __bf16 bf16x8 __attribute__((ext_vector_type(8)));
typedef float f32x4 __attribute__((ext_vector_type(4)));

__device__ __forceinline__ float dot4(f32x4 a, f32x4 b) {
    return a.x * b.x + a.y * b.y + a.z * b.z + a.w * b.w;
}

__device__ __forceinline__ void gload16(const void* g, void* lds) {
    __builtin_amdgcn_global_load_lds(
        (const __attribute__((address_space(1))) unsigned int*)g,
        (__attribute__((address_space(3))) unsigned int*)lds,
        16, 0, 0);
}
// NT/streaming variant for x (SLC bit): x is read-once; don't let it evict Vt in L2.
__device__ __forceinline__ void gload16_nt(const void* g, void* lds) {
    __builtin_amdgcn_global_load_lds(
        (const __attribute__((address_space(1))) unsigned int*)g,
        (__attribute__((address_space(3))) unsigned int*)lds,
        16, 0, 2);
}

// ---- prep: VtS[chunk kb][byte n*128 + ((kk*2) ^ ((n&7)<<4))] = bf16(V[kb*64+kk][n])
// (the swizzled LDS image itself, so main stages it with linear gload_lds)
// plus s[k] = sum_n V[k][n]^2
__global__ __launch_bounds__(256) void fm_prep(const float* __restrict__ V,
                                               char* __restrict__ VtS,
                                               float* __restrict__ s) {
    __shared__ float tile[64][132];
    const int t = threadIdx.x;
    const int kb = blockIdx.x;            // 32 blocks
    const int k0 = kb * 64;
#pragma unroll
    for (int i = 0; i < 8; ++i) {
        int idx = i * 256 + t;
        int kk = idx >> 5;
        int nq = (idx & 31) * 4;
        *(f32x4*)&tile[kk][nq] = *(const f32x4*)(V + (size_t)(k0 + kk) * N_DIM + nq);
    }
    __syncthreads();
    {
        const int n = t >> 1;
        const int half = t & 1;
        const int sw = (n & 7) << 4;
        char* dstbase = VtS + (size_t)kb * VT_CHUNK + n * 128;
#pragma unroll
        for (int g = 0; g < 4; ++g) {
            int kkg = half * 32 + g * 8;
            bf16x8 o;
#pragma unroll
            for (int e = 0; e < 8; ++e) o[e] = (__bf16)tile[kkg + e][n];
            *(bf16x8*)(dstbase + ((kkg * 2) ^ sw)) = o;
        }
    }
    if (t < 64) {
        float a = 0.f;
#pragma unroll
        for (int nq = 0; nq < 32; ++nq) {
            f32x4 v = *(f32x4*)&tile[t][nq * 4];
            a += dot4(v, v);
        }
        s[k0 + t] = a;
    }
}

// ---- main: block = 64 rows x 128 n x full K, 8 waves (wr=w>>1 row-group of 16,
// wc=w&1 n-half of 64). R12 post-mortem: fm_main time fits total_bytes/6.5TB/s
// across R2/R4/R6/R12 (x stream flushes L2 -> Vt re-fetches miss). Levers:
// BM=64 halves Vt traffic (256->128MB, grid 256 = 1 blk/CU, all CUs pull);
// NT on x loads protects Vt in L2. Counted-vmcnt pipeline kept from R12 so
// R4's per-tile drain stall doesn't return: x 3-deep (vmcnt(4): t+1 landed,
// t+2 in flight across barrier), Vt 2-deep vmcnt(0) (per-wave FIFO, m135).
__global__ __launch_bounds__(512, 2) void fm_main(const float* __restrict__ x,
                                                  const float* __restrict__ W,
                                                  const float* __restrict__ bptr,
                                                  const char* __restrict__ VtS,
                                                  const float* __restrict__ s,
                                                  float* __restrict__ out) {
    __shared__ __align__(16) char xbuf[3][16384];   // [64 rows][256B] swizzled, 3-deep
    __shared__ __align__(16) char vbuf[2][16384];   // [128 n][128B] swizzled, 2-deep
    __shared__ __align__(16) float Wl[2048];
    __shared__ __align__(16) float Sl[2048];
    __shared__ float lin_lds[4][16];
    __shared__ float sq_lds[4][16];
    __shared__ float ss_lds[4][2][16];

    const int tid = threadIdx.x;
    const int w = tid >> 6;
    const int l = tid & 63;
    const int lr = l & 15;
    const int lg = l >> 4;
    const int wr = w >> 1;      // 0..3 : row-group of 16
    const int wc = w & 1;       // 0..1 : n-half of 64
    const int row0 = blockIdx.x * BM;

    // W, s -> LDS first (their vmem waits retire before the pipeline gloads)
    *(f32x4*)&Wl[tid * 4] = *(const f32x4*)(W + tid * 4);
    *(f32x4*)&Sl[tid * 4] = *(const f32x4*)(s + tid * 4);

    // ---- staging: waves 0-3 stage x (16KB, 4 instrs/tile), waves 4-7 stage Vt (4/tile)
    const bool isX = (w < 4);
    const char* src[4];
    int loff[4];
    if (isX) {
#pragma unroll
        for (int j = 0; j < 4; ++j) {
            int gi = w * 4 + j;                 // 0..15
            int rowt = gi * 4 + lg;             // tile row this lane stages (0..63)
            int koff = (lr * 16) ^ ((rowt & 7) << 4);   // inverse-swizzled source
            src[j] = (const char*)x + (size_t)(row0 + rowt) * (K_DIM * 4) + koff;
            loff[j] = gi * 1024;
        }
    } else {
#pragma unroll
        for (int j = 0; j < 4; ++j) {
            int vi = (w - 4) * 4 + j;           // 0..15
            src[j] = VtS + vi * 1024 + l * 16;  // linear: global IS the LDS image
            loff[j] = vi * 1024;
        }
    }

    f32x4 acc[4];
#pragma unroll
    for (int c = 0; c < 4; ++c) acc[c] = (f32x4){0.f, 0.f, 0.f, 0.f};
    float lin = 0.f, sq = 0.f;

    // prologue: x tiles 0,1 -> slots 0,1 (keep tile1 in flight); Vt tile 0
    if (isX) {
#pragma unroll
        for (int j = 0; j < 4; ++j) gload16_nt(src[j], &xbuf[0][loff[j]]);
#pragma unroll
        for (int j = 0; j < 4; ++j) gload16_nt(src[j] + 256, &xbuf[1][loff[j]]);
        asm volatile("s_waitcnt vmcnt(4) lgkmcnt(0)" ::: "memory");
    } else {
#pragma unroll
        for (int j = 0; j < 4; ++j) gload16(src[j], &vbuf[0][loff[j]]);
        asm volatile("s_waitcnt vmcnt(0) lgkmcnt(0)" ::: "memory");
    }
    __builtin_amdgcn_s_barrier();
    __builtin_amdgcn_sched_barrier(0);

    const int rowt = wr * 16 + lr;
    const int swA = (rowt & 7) << 4;

    int xr = 0, xi = 2, vr = 0;
    for (int t = 0; t < NTILES; ++t) {
        // issue-ahead: x[t+2] -> slot xi (NT), Vt[t+1] -> other v-slot
        if (isX) {
            if (t + 2 < NTILES) {
#pragma unroll
                for (int j = 0; j < 4; ++j)
                    gload16_nt(src[j] + (size_t)(t + 2) * (BK * 4), &xbuf[xi][loff[j]]);
            }
        } else {
            if (t + 1 < NTILES) {
#pragma unroll
                for (int j = 0; j < 4; ++j)
                    gload16(src[j] + (size_t)(t + 1) * VT_CHUNK, &vbuf[vr ^ 1][loff[j]]);
            }
        }

        // ---- compute tile t
        const char* arow = &xbuf[xr][0] + rowt * 256;
        const char* vb = &vbuf[vr][0];

        bf16x8 af[2];
        f32x4 alo[2], ahi[2];
#pragma unroll
        for (int kb = 0; kb < 2; ++kb) {
            const int kA = kb * 128 + lg * 32;
            alo[kb] = *(const f32x4*)(arow + (kA ^ swA));
            ahi[kb] = *(const f32x4*)(arow + ((kA + 16) ^ swA));
            af[kb][0] = (__bf16)alo[kb].x; af[kb][1] = (__bf16)alo[kb].y;
            af[kb][2] = (__bf16)alo[kb].z; af[kb][3] = (__bf16)alo[kb].w;
            af[kb][4] = (__bf16)ahi[kb].x; af[kb][5] = (__bf16)ahi[kb].y;
            af[kb][6] = (__bf16)ahi[kb].z; af[kb][7] = (__bf16)ahi[kb].w;
        }
        if (wc == 0) {   // one n-half owns the lin/sq accumulation (wr covers distinct rows)
            const int ki = t * 64 + lg * 8;
#pragma unroll
            for (int kb = 0; kb < 2; ++kb) {
                f32x4 w0 = *(const f32x4*)&Wl[ki + kb * 32];
                f32x4 w1 = *(const f32x4*)&Wl[ki + kb * 32 + 4];
                f32x4 s0 = *(const f32x4*)&Sl[ki + kb * 32];
                f32x4 s1 = *(const f32x4*)&Sl[ki + kb * 32 + 4];
                lin += dot4(alo[kb], w0) + dot4(ahi[kb], w1);
                sq  += dot4(alo[kb] * alo[kb], s0) + dot4(ahi[kb] * ahi[kb], s1);
            }
        }
#pragma unroll
        for (int c = 0; c < 4; ++c) {
            const int nt = wc * 64 + c * 16 + lr;
            const int swB = (nt & 7) << 4;
            const char* brow = vb + nt * 128;
#pragma unroll
            for (int kb = 0; kb < 2; ++kb) {
                bf16x8 bf = *(const bf16x8*)(brow + ((kb * 64 + lg * 16) ^ swB));
                acc[c] = __builtin_amdgcn_mfma_f32_16x16x32_bf16(af[kb], bf, acc[c], 0, 0, 0);
            }
        }

        // ---- counted-vmcnt sync: t+1's data ready, t+2's stays in flight
        if (t < NTILES - 1) {
            if (isX) {
                if (t + 2 < NTILES)
                    asm volatile("s_waitcnt vmcnt(4)" ::: "memory");
                else
                    asm volatile("s_waitcnt vmcnt(0)" ::: "memory");
            } else {
                asm volatile("s_waitcnt vmcnt(0)" ::: "memory");
            }
            __builtin_amdgcn_s_barrier();
            __builtin_amdgcn_sched_barrier(0);
        }
        xr = (xr == 2) ? 0 : xr + 1;
        xi = (xi == 2) ? 0 : xi + 1;
        vr ^= 1;
    }

    // ---- epilogue. C/D layout (m89, verified R2..R12): out-row = lg*4+j, out-col(n) = lr
    f32x4 vss = (f32x4){0.f, 0.f, 0.f, 0.f};
#pragma unroll
    for (int c = 0; c < 4; ++c) vss += acc[c] * acc[c];
#pragma unroll
    for (int m = 1; m < 16; m <<= 1) {
        vss.x += __shfl_xor(vss.x, m);
        vss.y += __shfl_xor(vss.y, m);
        vss.z += __shfl_xor(vss.z, m);
        vss.w += __shfl_xor(vss.w, m);
    }
    if (lr == 0) {
        ss_lds[wr][wc][lg * 4 + 0] = vss.x;
        ss_lds[wr][wc][lg * 4 + 1] = vss.y;
        ss_lds[wr][wc][lg * 4 + 2] = vss.z;
        ss_lds[wr][wc][lg * 4 + 3] = vss.w;
    }
    if (wc == 0) {
        lin += __shfl_xor(lin, 16); lin += __shfl_xor(lin, 32);
        sq  += __shfl_xor(sq, 16);  sq  += __shfl_xor(sq, 32);
        if (l < 16) { lin_lds[wr][l] = lin; sq_lds[wr][l] = sq; }
    }
    __syncthreads();
    if (tid < BM) {
        const int wrI = tid >> 4, r16 = tid & 15;
        out[row0 + tid] = lin_lds[wrI][r16] + bptr[0]
            + 0.5f * (ss_lds[wrI][0][r16] + ss_lds[wrI][1][r16]
                      - sq_lds[wrI][r16]);
    }
}

extern "C" void kernel_launch(void* const* d_in, const int* in_sizes, int n_in,
                              void* d_out, int out_size, void* d_ws, size_t ws_size,
                              hipStream_t stream) {
    const float* x = (const float*)d_in[0];
    const float* W = (const float*)d_in[1];
    const float* b = (const float*)d_in[2];
    const float* V = (const float*)d_in[3];
    float* out = (float*)d_out;

    char* VtS = (char*)d_ws;                                  // 32 chunks * 16KB = 512KB
    float* s = (float*)((char*)d_ws + 32 * VT_CHUNK);         // 8KB

    fm_prep<<<32, 256, 0, stream>>>(V, VtS, s);
    fm_main<<<256, 512, 0, stream>>>(x, W, b, VtS, s, out);
}